// Round 9
// baseline (424.678 us; speedup 1.0000x reference)
//
#include <hip/hip_runtime.h>

#define DIN 128
#define BN_EPS 1e-5f

#define AM_CVT    1
#define AM_BN     2
#define AM_BNHALF 3

typedef __attribute__((ext_vector_type(8))) short bf16x8;
typedef __attribute__((ext_vector_type(4))) float f32x4;

__device__ __forceinline__ ushort f2bf(float f) {
    unsigned u = __float_as_uint(f);
    u += 0x7fffu + ((u >> 16) & 1u);
    return (ushort)(u >> 16);
}
__device__ __forceinline__ float bf2f(ushort h) {
    return __uint_as_float(((unsigned)h) << 16);
}

// ======== barrier-free streaming GEMM with consumer-side BN+act on the A path ========
// C[M,N](bf16) = act(bn(A))[M,K] @ BT[N,K]^T
// AM_CVT:    A32 fp32 -> bf16 inline (no bn)
// AM_BN:     A bf16, v = bf2f(a)*scale[k]+shift[k], act(negSlope), repack bf16
// AM_BNHALF: kc<KC/2 as AM_BN from A (stride 128); kc>=KC/2 raw from A2 (stride 128)
template<int KC, int STATS, int AMODE>
__global__ __launch_bounds__(256) void gemm_wreg(
    const ushort* __restrict__ A, const float* __restrict__ A32,
    const ushort* __restrict__ A2,
    const float* __restrict__ bnscale, const float* __restrict__ bnshift, float negSlope,
    const ushort* __restrict__ BT,
    ushort* __restrict__ C, int mStrips, int N, int K, int logNG,
    float* __restrict__ gsums, float* __restrict__ gsqs)
{
    int tid = threadIdx.x;
    int lane = tid & 63;
    int gw = blockIdx.x * 4 + (tid >> 6);
    int wg = gw & ((1 << logNG) - 1);
    int set = gw >> logNG;
    int totalSets = (gridDim.x * 4) >> logNG;
    int cl = lane & 15, q = lane >> 4;
    int colBase = wg * 64;

    bf16x8 bf[4][KC];
    #pragma unroll
    for (int nt = 0; nt < 4; nt++) {
        const ushort* bp = BT + (long)(colBase + nt * 16 + cl) * K + q * 8;
        #pragma unroll
        for (int kc = 0; kc < KC; kc++)
            bf[nt][kc] = *(const bf16x8*)(bp + kc * 32);
    }

    float ssum[4] = {0.f, 0.f, 0.f, 0.f};
    float ssq[4]  = {0.f, 0.f, 0.f, 0.f};

    for (int strip = set; strip < mStrips; strip += totalSets) {
        int rowBase = strip * 16;
        bf16x8 af[KC];
        if (AMODE == AM_CVT) {
            const float* ap = A32 + (long)(rowBase + cl) * K + q * 8;
            #pragma unroll
            for (int kc = 0; kc < KC; kc++) {
                float4 v0 = *(const float4*)(ap + kc * 32);
                float4 v1 = *(const float4*)(ap + kc * 32 + 4);
                ushort* o = (ushort*)&af[kc];
                o[0] = f2bf(v0.x); o[1] = f2bf(v0.y); o[2] = f2bf(v0.z); o[3] = f2bf(v0.w);
                o[4] = f2bf(v1.x); o[5] = f2bf(v1.y); o[6] = f2bf(v1.z); o[7] = f2bf(v1.w);
            }
        } else if (AMODE == AM_BN) {
            const ushort* ap = A + (long)(rowBase + cl) * K + q * 8;
            #pragma unroll
            for (int kc = 0; kc < KC; kc++) {
                bf16x8 raw = *(const bf16x8*)(ap + kc * 32);
                int k0 = kc * 32 + q * 8;
                float4 s0 = *(const float4*)(bnscale + k0);
                float4 s1 = *(const float4*)(bnscale + k0 + 4);
                float4 h0 = *(const float4*)(bnshift + k0);
                float4 h1 = *(const float4*)(bnshift + k0 + 4);
                const ushort* r = (const ushort*)&raw;
                ushort* o = (ushort*)&af[kc];
                float v;
                v = bf2f(r[0]) * s0.x + h0.x; v = (v > 0.f) ? v : v * negSlope; o[0] = f2bf(v);
                v = bf2f(r[1]) * s0.y + h0.y; v = (v > 0.f) ? v : v * negSlope; o[1] = f2bf(v);
                v = bf2f(r[2]) * s0.z + h0.z; v = (v > 0.f) ? v : v * negSlope; o[2] = f2bf(v);
                v = bf2f(r[3]) * s0.w + h0.w; v = (v > 0.f) ? v : v * negSlope; o[3] = f2bf(v);
                v = bf2f(r[4]) * s1.x + h1.x; v = (v > 0.f) ? v : v * negSlope; o[4] = f2bf(v);
                v = bf2f(r[5]) * s1.y + h1.y; v = (v > 0.f) ? v : v * negSlope; o[5] = f2bf(v);
                v = bf2f(r[6]) * s1.z + h1.z; v = (v > 0.f) ? v : v * negSlope; o[6] = f2bf(v);
                v = bf2f(r[7]) * s1.w + h1.w; v = (v > 0.f) ? v : v * negSlope; o[7] = f2bf(v);
            }
        } else { // AM_BNHALF: A stride 128 transformed, A2 stride 128 raw
            const ushort* ap  = A  + (long)(rowBase + cl) * 128 + q * 8;
            const ushort* ap2 = A2 + (long)(rowBase + cl) * 128 + q * 8;
            #pragma unroll
            for (int kc = 0; kc < KC / 2; kc++) {
                bf16x8 raw = *(const bf16x8*)(ap + kc * 32);
                int k0 = kc * 32 + q * 8;
                float4 s0 = *(const float4*)(bnscale + k0);
                float4 s1 = *(const float4*)(bnscale + k0 + 4);
                float4 h0 = *(const float4*)(bnshift + k0);
                float4 h1 = *(const float4*)(bnshift + k0 + 4);
                const ushort* r = (const ushort*)&raw;
                ushort* o = (ushort*)&af[kc];
                float v;
                v = bf2f(r[0]) * s0.x + h0.x; v = (v > 0.f) ? v : 0.f; o[0] = f2bf(v);
                v = bf2f(r[1]) * s0.y + h0.y; v = (v > 0.f) ? v : 0.f; o[1] = f2bf(v);
                v = bf2f(r[2]) * s0.z + h0.z; v = (v > 0.f) ? v : 0.f; o[2] = f2bf(v);
                v = bf2f(r[3]) * s0.w + h0.w; v = (v > 0.f) ? v : 0.f; o[3] = f2bf(v);
                v = bf2f(r[4]) * s1.x + h1.x; v = (v > 0.f) ? v : 0.f; o[4] = f2bf(v);
                v = bf2f(r[5]) * s1.y + h1.y; v = (v > 0.f) ? v : 0.f; o[5] = f2bf(v);
                v = bf2f(r[6]) * s1.z + h1.z; v = (v > 0.f) ? v : 0.f; o[6] = f2bf(v);
                v = bf2f(r[7]) * s1.w + h1.w; v = (v > 0.f) ? v : 0.f; o[7] = f2bf(v);
            }
            #pragma unroll
            for (int kc = KC / 2; kc < KC; kc++)
                af[kc] = *(const bf16x8*)(ap2 + (kc - KC / 2) * 32);
        }

        f32x4 acc[4] = {};
        #pragma unroll
        for (int kc = 0; kc < KC; kc++)
            #pragma unroll
            for (int nt = 0; nt < 4; nt++)
                acc[nt] = __builtin_amdgcn_mfma_f32_16x16x32_bf16(af[kc], bf[nt][kc], acc[nt], 0, 0, 0);
        #pragma unroll
        for (int nt = 0; nt < 4; nt++) {
            #pragma unroll
            for (int r = 0; r < 4; r++) {
                float v = acc[nt][r];
                long row = rowBase + q * 4 + r;
                C[row * N + colBase + nt * 16 + cl] = f2bf(v);
                if (STATS) { ssum[nt] += v; ssq[nt] += v * v; }
            }
        }
    }

    if (STATS) {
        #pragma unroll
        for (int nt = 0; nt < 4; nt++) {
            ssum[nt] += __shfl_xor(ssum[nt], 16, 64);
            ssum[nt] += __shfl_xor(ssum[nt], 32, 64);
            ssq[nt]  += __shfl_xor(ssq[nt], 16, 64);
            ssq[nt]  += __shfl_xor(ssq[nt], 32, 64);
        }
        if (q == 0) {
            #pragma unroll
            for (int nt = 0; nt < 4; nt++) {
                atomicAdd(&gsums[colBase + nt * 16 + cl], ssum[nt]);
                atomicAdd(&gsqs[colBase + nt * 16 + cl], ssq[nt]);
            }
        }
    }
}

// ======== BN params (kept separate — round-7 lesson) ========
__global__ void bnparam_kernel(const float* __restrict__ sums, const float* __restrict__ sqs,
                               const float* __restrict__ gamma, const float* __restrict__ beta,
                               float* __restrict__ scale, float* __restrict__ shift,
                               int N, float invM)
{
    int c = blockIdx.x * blockDim.x + threadIdx.x;
    if (c < N) {
        float mean = sums[c] * invM;
        float var = sqs[c] * invM - mean * mean;
        float sc = gamma[c] * rsqrtf(var + BN_EPS);
        scale[c] = sc;
        shift[c] = beta[c] - mean * sc;
    }
}

// ======== BN + act, fp32 in-place (final output) ========
__global__ __launch_bounds__(256) void bnact_f32(
    float* __restrict__ X, const float* __restrict__ scale, const float* __restrict__ shift,
    int total4, int logN, float negSlope)
{
    int stride = gridDim.x * blockDim.x;
    int Nm1 = (1 << logN) - 1;
    for (int t = blockIdx.x * blockDim.x + threadIdx.x; t < total4; t += stride) {
        int idx = t * 4;
        int c = idx & Nm1;
        float4 v = *(const float4*)&X[idx];
        float4 sc = *(const float4*)&scale[c];
        float4 sh = *(const float4*)&shift[c];
        float a = v.x * sc.x + sh.x; a = (a > 0.f) ? a : a * negSlope;
        float b = v.y * sc.y + sh.y; b = (b > 0.f) ? b : b * negSlope;
        float d = v.z * sc.z + sh.z; d = (d > 0.f) ? d : d * negSlope;
        float e = v.w * sc.w + sh.w; e = (e > 0.f) ? e : e * negSlope;
        *(float4*)&X[idx] = make_float4(a, b, d, e);
    }
}

// ======== column stats for final output (128 cols, register accum) ========
__global__ __launch_bounds__(256) void colstats128(
    const float* __restrict__ X, float* __restrict__ sums, float* __restrict__ sqs, int M)
{
    __shared__ float ss[128], sq[128];
    int tid = threadIdx.x;
    if (tid < 128) { ss[tid] = 0.f; sq[tid] = 0.f; }
    __syncthreads();
    int cg = tid & 31;
    int worker = (blockIdx.x << 3) | (tid >> 5);
    int totalW = gridDim.x << 3;
    float4 s4 = make_float4(0, 0, 0, 0), q4 = make_float4(0, 0, 0, 0);
    for (int r = worker; r < M; r += totalW) {
        float4 v = *(const float4*)&X[(long)r * 128 + cg * 4];
        s4.x += v.x; s4.y += v.y; s4.z += v.z; s4.w += v.w;
        q4.x += v.x * v.x; q4.y += v.y * v.y; q4.z += v.z * v.z; q4.w += v.w * v.w;
    }
    atomicAdd(&ss[cg * 4 + 0], s4.x); atomicAdd(&sq[cg * 4 + 0], q4.x);
    atomicAdd(&ss[cg * 4 + 1], s4.y); atomicAdd(&sq[cg * 4 + 1], q4.y);
    atomicAdd(&ss[cg * 4 + 2], s4.z); atomicAdd(&sq[cg * 4 + 2], q4.z);
    atomicAdd(&ss[cg * 4 + 3], s4.w); atomicAdd(&sq[cg * 4 + 3], q4.w);
    __syncthreads();
    if (tid < 128) { atomicAdd(&sums[tid], ss[tid]); atomicAdd(&sqs[tid], sq[tid]); }
}

__global__ void wt_all(const float* __restrict__ W0, const float* __restrict__ W1,
                       const float* __restrict__ W2, const float* __restrict__ W3,
                       const float* __restrict__ W4, const float* __restrict__ W5,
                       ushort* __restrict__ WT)
{
    int seg = blockIdx.y;
    const float* W; int logK, dstBase, stride, kOff;
    switch (seg) {
        case 0: W = W0; logK = 7; dstBase = 0;      stride = 128; kOff = 0;   break;
        case 1: W = W1; logK = 8; dstBase = 32768;  stride = 256; kOff = 0;   break;
        case 2: W = W2; logK = 7; dstBase = 65536;  stride = 256; kOff = 0;   break;
        case 3: W = W3; logK = 7; dstBase = 65536;  stride = 256; kOff = 128; break;
        case 4: W = W4; logK = 8; dstBase = 131072; stride = 256; kOff = 0;   break;
        default:W = W5; logK = 8; dstBase = 163840; stride = 256; kOff = 0;   break;
    }
    int t = blockIdx.x * blockDim.x + threadIdx.x;
    int N = 32768 >> logK;
    int k = t & ((1 << logK) - 1);
    int n = t >> logK;
    WT[(long)dstBase + (long)n * stride + kOff + k] = f2bf(W[(long)k * N + n]);
}

// ======== CSR build ========
__global__ void degcount_kernel(const int* __restrict__ dst, int* __restrict__ degi, int E)
{
    int i = blockIdx.x * blockDim.x + threadIdx.x;
    if (i < E) atomicAdd(&degi[dst[i]], 1);
}

__global__ __launch_bounds__(256) void scan_block_sums(const int* __restrict__ degi,
                                                       int* __restrict__ partial, int n)
{
    __shared__ int s[256];
    int i = blockIdx.x * 256 + threadIdx.x;
    s[threadIdx.x] = (i < n) ? degi[i] : 0;
    __syncthreads();
    for (int off = 128; off > 0; off >>= 1) {
        if (threadIdx.x < off) s[threadIdx.x] += s[threadIdx.x + off];
        __syncthreads();
    }
    if (threadIdx.x == 0) partial[blockIdx.x] = s[0];
}

__global__ __launch_bounds__(256) void scan_partials(int* __restrict__ partial, int nb)
{
    __shared__ int s[256];
    int v = (threadIdx.x < nb) ? partial[threadIdx.x] : 0;
    s[threadIdx.x] = v;
    __syncthreads();
    for (int off = 1; off < 256; off <<= 1) {
        int t = (threadIdx.x >= off) ? s[threadIdx.x - off] : 0;
        __syncthreads();
        s[threadIdx.x] += t;
        __syncthreads();
    }
    if (threadIdx.x < nb) partial[threadIdx.x] = s[threadIdx.x] - v;
}

__global__ __launch_bounds__(256) void scan_final(const int* __restrict__ degi,
                                                  const int* __restrict__ partial,
                                                  int* __restrict__ rowstart, int n)
{
    __shared__ int s[256];
    int i = blockIdx.x * 256 + threadIdx.x;
    int v = (i < n) ? degi[i] : 0;
    s[threadIdx.x] = v;
    __syncthreads();
    for (int off = 1; off < 256; off <<= 1) {
        int t = (threadIdx.x >= off) ? s[threadIdx.x - off] : 0;
        __syncthreads();
        s[threadIdx.x] += t;
        __syncthreads();
    }
    if (i < n) rowstart[i] = partial[blockIdx.x] + s[threadIdx.x] - v;
}

__global__ void fillcsr_kernel(const int* __restrict__ src, const int* __restrict__ dst,
                               const int* __restrict__ rowstart, int* __restrict__ cursor,
                               int* __restrict__ csr, int E)
{
    int i = blockIdx.x * blockDim.x + threadIdx.x;
    if (i < E) {
        int d = dst[i];
        int p = atomicAdd(&cursor[d], 1);
        csr[rowstart[d] + p] = src[i];
    }
}

// ======== gather1 with inline BN+ReLU: AGG[v] = mean over nbrs of relu(bn(PRE2[s])) ========
__global__ __launch_bounds__(256) void gather_bn(
    const ushort* __restrict__ PRE2, const float* __restrict__ scale, const float* __restrict__ shift,
    const int* __restrict__ rowstart, const int* __restrict__ degi, const int* __restrict__ csr,
    ushort* __restrict__ AGG, int nN)
{
    int wv = (blockIdx.x * blockDim.x + threadIdx.x) >> 6;
    int lane = threadIdx.x & 63;
    if (wv >= nN) return;
    int start = rowstart[wv], d = degi[wv];
    int col = lane * 2;
    float sc0 = scale[col], sc1 = scale[col + 1];
    float sh0 = shift[col], sh1 = shift[col + 1];
    float a0 = 0.f, a1 = 0.f;
    int j = 0;
    for (; j + 4 <= d; j += 4) {
        int s0 = csr[start + j + 0];
        int s1 = csr[start + j + 1];
        int s2 = csr[start + j + 2];
        int s3 = csr[start + j + 3];
        unsigned p0 = *(const unsigned*)(PRE2 + (long)s0 * 128 + col);
        unsigned p1 = *(const unsigned*)(PRE2 + (long)s1 * 128 + col);
        unsigned p2 = *(const unsigned*)(PRE2 + (long)s2 * 128 + col);
        unsigned p3 = *(const unsigned*)(PRE2 + (long)s3 * 128 + col);
        a0 += fmaxf(bf2f((ushort)(p0 & 0xffff)) * sc0 + sh0, 0.f)
            + fmaxf(bf2f((ushort)(p1 & 0xffff)) * sc0 + sh0, 0.f)
            + fmaxf(bf2f((ushort)(p2 & 0xffff)) * sc0 + sh0, 0.f)
            + fmaxf(bf2f((ushort)(p3 & 0xffff)) * sc0 + sh0, 0.f);
        a1 += fmaxf(bf2f((ushort)(p0 >> 16)) * sc1 + sh1, 0.f)
            + fmaxf(bf2f((ushort)(p1 >> 16)) * sc1 + sh1, 0.f)
            + fmaxf(bf2f((ushort)(p2 >> 16)) * sc1 + sh1, 0.f)
            + fmaxf(bf2f((ushort)(p3 >> 16)) * sc1 + sh1, 0.f);
    }
    for (; j < d; j++) {
        int s0 = csr[start + j];
        unsigned p0 = *(const unsigned*)(PRE2 + (long)s0 * 128 + col);
        a0 += fmaxf(bf2f((ushort)(p0 & 0xffff)) * sc0 + sh0, 0.f);
        a1 += fmaxf(bf2f((ushort)(p0 >> 16)) * sc1 + sh1, 0.f);
    }
    float inv = 1.f / fmaxf((float)d, 1.f);
    unsigned o = (unsigned)f2bf(a0 * inv) | ((unsigned)f2bf(a1 * inv) << 16);
    *(unsigned*)(AGG + (long)wv * 128 + col) = o;
}

// ======== fused gather2: out = mean(Z[src, 0:128]) + Z[dst, 128:256], unroll-4 ========
__global__ __launch_bounds__(256) void gather_fuse(
    const ushort* __restrict__ Z, const int* __restrict__ rowstart,
    const int* __restrict__ degi, const int* __restrict__ csr,
    float* __restrict__ O, int nN)
{
    int wv = (blockIdx.x * blockDim.x + threadIdx.x) >> 6;
    int lane = threadIdx.x & 63;
    if (wv >= nN) return;
    int start = rowstart[wv], d = degi[wv];
    float a0 = 0.f, a1 = 0.f;
    int col = lane * 2;
    int j = 0;
    for (; j + 4 <= d; j += 4) {
        int s0 = csr[start + j + 0];
        int s1 = csr[start + j + 1];
        int s2 = csr[start + j + 2];
        int s3 = csr[start + j + 3];
        unsigned p0 = *(const unsigned*)(Z + (long)s0 * 256 + col);
        unsigned p1 = *(const unsigned*)(Z + (long)s1 * 256 + col);
        unsigned p2 = *(const unsigned*)(Z + (long)s2 * 256 + col);
        unsigned p3 = *(const unsigned*)(Z + (long)s3 * 256 + col);
        a0 += bf2f((ushort)(p0 & 0xffff)) + bf2f((ushort)(p1 & 0xffff))
            + bf2f((ushort)(p2 & 0xffff)) + bf2f((ushort)(p3 & 0xffff));
        a1 += bf2f((ushort)(p0 >> 16)) + bf2f((ushort)(p1 >> 16))
            + bf2f((ushort)(p2 >> 16)) + bf2f((ushort)(p3 >> 16));
    }
    for (; j < d; j++) {
        int s0 = csr[start + j];
        unsigned p0 = *(const unsigned*)(Z + (long)s0 * 256 + col);
        a0 += bf2f((ushort)(p0 & 0xffff));
        a1 += bf2f((ushort)(p0 >> 16));
    }
    float inv = 1.f / fmaxf((float)d, 1.f);
    unsigned sv = *(const unsigned*)(Z + (long)wv * 256 + 128 + col);
    float s0 = bf2f((ushort)(sv & 0xffff));
    float s1 = bf2f((ushort)(sv >> 16));
    *(float2*)(O + (long)wv * 128 + col) = make_float2(a0 * inv + s0, a1 * inv + s1);
}

extern "C" void kernel_launch(void* const* d_in, const int* in_sizes, int n_in,
                              void* d_out, int out_size, void* d_ws, size_t ws_size,
                              hipStream_t stream)
{
    const float* nodes = (const float*)d_in[0];
    const int*   src   = (const int*)d_in[1];
    const int*   dst   = (const int*)d_in[2];
    const float* Wf1   = (const float*)d_in[3];
    const float* gf1   = (const float*)d_in[5];
    const float* bef1  = (const float*)d_in[6];
    const float* Wf2   = (const float*)d_in[7];
    const float* gf2   = (const float*)d_in[9];
    const float* bef2  = (const float*)d_in[10];
    const float* Ws1   = (const float*)d_in[11];
    const float* Wn1   = (const float*)d_in[12];
    const float* gs1   = (const float*)d_in[14];
    const float* bs1   = (const float*)d_in[15];
    const float* Ws2   = (const float*)d_in[16];
    const float* Wn2   = (const float*)d_in[17];
    const float* gs2   = (const float*)d_in[19];
    const float* bs2   = (const float*)d_in[20];
    // pre-BN biases (bf1,bf2,b1,b2) cancel under BatchNorm -> skipped

    int nN = in_sizes[0] / DIN;   // 50000
    int nE = in_sizes[1];         // 600000
    float* out = (float*)d_out;
    int mStrips = nN / 16;        // 3125 (exact)
    float invM = 1.0f / nN;

    // ---- workspace ----
    ushort* PRE1 = (ushort*)d_ws;                     // nN*256 (FF1 out; reused as PRE3)
    ushort* PRE2 = PRE1 + (size_t)nN * 256;           // nN*128 (FF2 out, pre-BN)
    ushort* AGG  = PRE2 + (size_t)nN * 128;           // nN*128 (gather1 out, post-BN mean)
    ushort* Z    = AGG + (size_t)nN * 128;            // nN*256 (SAGE2 out)
    float* scales = (float*)(Z + (size_t)nN * 256);   // 4*256
    float* shifts = scales + 4 * 256;                 // 4*256
    float* stats  = shifts + 4 * 256;                 // 2048 (zero region start)
    int* degi     = (int*)(stats + 2048);             // nN   (zero region)
    int* cursor   = degi + nN;                        // nN   (zero region end)
    int* rowstart = cursor + nN;                      // nN
    int* partial  = rowstart + nN;                    // 256
    int* csr      = partial + 256;                    // nE
    ushort* WT    = (ushort*)(csr + nE);              // 196608

    ushort* PRE3 = PRE1;   // PRE1 dead after FF2
    ushort* Wf1T = WT;
    ushort* Wf2T = WT + 32768;
    ushort* Wc1T = WT + 65536;
    ushort* Wc2T = WT + 131072;

    dim3 blk(256);
    auto cdiv = [](int a, int b) { return (a + b - 1) / b; };
    int nScanBlocks = cdiv(nN, 256);

    // ---- weight transpose + one contiguous zero-init (stats|degi|cursor) ----
    wt_all<<<dim3(128, 6), blk, 0, stream>>>(Wf1, Wf2, Ws1, Wn1, Wn2, Ws2, WT);
    hipMemsetAsync(stats, 0, 2048 * sizeof(float) + 2 * (size_t)nN * sizeof(int), stream);

    // ---- CSR build ----
    degcount_kernel<<<dim3(cdiv(nE, 256)), blk, 0, stream>>>(dst, degi, nE);
    scan_block_sums<<<dim3(nScanBlocks), blk, 0, stream>>>(degi, partial, nN);
    scan_partials<<<dim3(1), blk, 0, stream>>>(partial, nScanBlocks);
    scan_final<<<dim3(nScanBlocks), blk, 0, stream>>>(degi, partial, rowstart, nN);
    fillcsr_kernel<<<dim3(cdiv(nE, 256)), blk, 0, stream>>>(src, dst, rowstart, cursor, csr, nE);

    // ---- FF1: PRE1 = bf16(nodes) @ Wf1T (inline fp32->bf16; K=128, N=256, stats->L0) ----
    gemm_wreg<4, 1, AM_CVT><<<dim3(512), blk, 0, stream>>>(
        nullptr, nodes, nullptr, nullptr, nullptr, 0.0f,
        Wf1T, PRE1, mStrips, 256, 128, 2, stats, stats + 256);
    bnparam_kernel<<<dim3(1), blk, 0, stream>>>(stats, stats + 256, gf1, bef1,
                                                scales, shifts, 256, invM);

    // ---- FF2: PRE2 = relu(bn0(PRE1)) @ Wf2T (inline; K=256, N=128, stats->L1) ----
    gemm_wreg<8, 1, AM_BN><<<dim3(256), blk, 0, stream>>>(
        PRE1, nullptr, nullptr, scales, shifts, 0.0f,
        Wf2T, PRE2, mStrips, 128, 256, 1, stats + 512, stats + 768);
    bnparam_kernel<<<dim3(1), blk, 0, stream>>>(stats + 512, stats + 768, gf2, bef2,
                                                scales + 256, shifts + 256, 128, invM);

    // ---- gather1 (inline bn1+relu): AGG = mean-gather(relu(bn1(PRE2))) ----
    gather_bn<<<dim3(cdiv(nN * 64, 256)), blk, 0, stream>>>(
        PRE2, scales + 256, shifts + 256, rowstart, degi, csr, AGG, nN);

    // ---- SAGE1: PRE3 = [relu(bn1(PRE2)) | AGG] @ Wc1T (inline half; K=256, N=256, stats->L2) ----
    gemm_wreg<8, 1, AM_BNHALF><<<dim3(512), blk, 0, stream>>>(
        PRE2, nullptr, AGG, scales + 256, shifts + 256, 0.0f,
        Wc1T, PRE3, mStrips, 256, 256, 2, stats + 1024, stats + 1280);
    bnparam_kernel<<<dim3(1), blk, 0, stream>>>(stats + 1024, stats + 1280, gs1, bs1,
                                                scales + 512, shifts + 512, 256, invM);

    // ---- SAGE2: Z = lrelu(bn2(PRE3)) @ Wc2T (inline; K=256, N=256, no stats) ----
    gemm_wreg<8, 0, AM_BN><<<dim3(512), blk, 0, stream>>>(
        PRE3, nullptr, nullptr, scales + 512, shifts + 512, 0.01f,
        Wc2T, Z, mStrips, 256, 256, 2, nullptr, nullptr);

    // ---- gather_fuse -> out (fp32) ----
    gather_fuse<<<dim3(cdiv(nN * 64, 256)), blk, 0, stream>>>(Z, rowstart, degi, csr, out, nN);

    // ---- final: colstats -> BN params -> BN+LReLU on out ----
    colstats128<<<dim3(120), blk, 0, stream>>>(out, stats + 1536, stats + 1792, nN);
    bnparam_kernel<<<dim3(1), blk, 0, stream>>>(stats + 1536, stats + 1792, gs2, bs2,
                                                scales + 768, shifts + 768, 128, invM);
    bnact_f32<<<dim3(2048), blk, 0, stream>>>(out, scales + 768, shifts + 768,
                                              nN * 128 / 4, 7, 0.01f);
}